// Round 5
// baseline (182.084 us; speedup 1.0000x reference)
//
#include <hip/hip_runtime.h>

// MultiHeadAttention: out = softmax((XWq^T)(XWk^T)^T / 8) (XWv^T) Wo^T
// B=2, L=2048, DIM=1024, H=16, D=64. fp32 in/out, bf16 MFMA compute.
//
// R16: (a) gemm_qkv REVERTED to R11/R14 single-buffer 32KB form (R15's
//      2-phase 64KB dbuf cut co-residency 3->2 blocks/CU and regressed
//      44.6->51.4us; inter-block TLP was hiding the drain better than
//      intra-block overlap). (b) gemm_o rewritten: 128x128 tile -> grid 256
//      = 1 block/CU single round (was 512 blocks / 2 rounds); at 1 block/CU
//      there is no TLP to lose, so 2-phase 64KB dbuf IS right here; swapped
//      MFMA (C^T) -> float4 coalesced fp32 stores. attn9/cvt_all unchanged.

#define DIMN 1024
#define NH 16
#define HD 64
#define BB 2
#define LL 2048

typedef float f32x4 __attribute__((ext_vector_type(4)));
typedef short s16x8 __attribute__((ext_vector_type(8)));

#define QSCALE 0.18033688011112042f  // log2(e)/8, folds softmax exp2 domain

static __device__ __forceinline__ unsigned short f2bf(float f) {
  unsigned u = __float_as_uint(f);
  u += 0x7fffu + ((u >> 16) & 1u);   // RNE
  return (unsigned short)(u >> 16);
}
static __device__ __forceinline__ unsigned packbf2(float lo, float hi) {
  return (unsigned)f2bf(lo) | ((unsigned)f2bf(hi) << 16);
}
static __device__ __forceinline__ float xexp2(float x) {
#if __has_builtin(__builtin_amdgcn_exp2f)
  return __builtin_amdgcn_exp2f(x);
#else
  return exp2f(x);
#endif
}
static __device__ __forceinline__ s16x8 cvt8(float4 a, float4 b) {
  s16x8 r;
  r[0] = (short)f2bf(a.x); r[1] = (short)f2bf(a.y);
  r[2] = (short)f2bf(a.z); r[3] = (short)f2bf(a.w);
  r[4] = (short)f2bf(b.x); r[5] = (short)f2bf(b.y);
  r[6] = (short)f2bf(b.z); r[7] = (short)f2bf(b.w);
  return r;
}
// async global->LDS, 16B/lane; LDS dest is wave-uniform base + lane*16
static __device__ __forceinline__ void gld16(const unsigned short* g,
                                             unsigned short* l) {
#if __has_builtin(__builtin_amdgcn_global_load_lds)
  __builtin_amdgcn_global_load_lds(
      (const __attribute__((address_space(1))) void*)g,
      (__attribute__((address_space(3))) void*)l, 16, 0, 0);
#else
  ((uint4*)l)[threadIdx.x & 63] = ((const uint4*)g)[0];
#endif
}

// V storage permutation within each 128-seq group (bits of s):
// pos = b6*64 + b5*32 + (bits3:2)*8 + bit4*4 + bits1:0  — keeps low 2 bits.
// Note: preserves bit 6 -> decomposes into independent 64-seq sub-perms.
static __device__ __forceinline__ int vpos(int s128) {
  return (s128 & 0x60) | ((s128 & 0x0C) << 1) | ((s128 & 0x10) >> 2) | (s128 & 3);
}

// ---------------- fp32 -> bf16 pre-convert (X + 4 weights) ----------------
__global__ __launch_bounds__(256) void cvt_all(
    const float* __restrict__ X, const float* __restrict__ Wq,
    const float* __restrict__ Wk, const float* __restrict__ Wv,
    const float* __restrict__ Wo, unsigned short* __restrict__ out) {
  const int blk = blockIdx.x;
  const float* src;
  unsigned short* dst;
  size_t off;
  if (blk < 2048) {
    src = X; dst = out; off = (size_t)blk * 2048;
  } else {
    int s = (blk - 2048) >> 9;
    src = (s == 0) ? Wq : (s == 1) ? Wk : (s == 2) ? Wv : Wo;
    dst = out + ((size_t)1 << 22) + (size_t)s * (1u << 20);
    off = (size_t)((blk - 2048) & 511) * 2048;
  }
  size_t i = off + (size_t)threadIdx.x * 8;
  float4 v0 = *(const float4*)(src + i);
  float4 v1 = *(const float4*)(src + i + 4);
  uint4 o;
  o.x = packbf2(v0.x, v0.y); o.y = packbf2(v0.z, v0.w);
  o.z = packbf2(v1.x, v1.y); o.w = packbf2(v1.z, v1.w);
  *(uint4*)(dst + i) = o;
}

// ---------------- fused QKV projection, 128x128, BK=64 (R11 form) ----------
// grid 768 (1D, XCD-swizzled). Rows in LDS are 64 shorts (128 B), chunk-
// swizzled: phys slot p of row r holds logical chunk p ^ (r&7).
// Single-buffer 32KB -> 3 blocks/CU co-resident (TLP hides the drain).
__global__ __launch_bounds__(256) void gemm_qkv(
    const unsigned short* __restrict__ Xb, const unsigned short* __restrict__ Wb,
    unsigned short* __restrict__ Qb, unsigned short* __restrict__ Kb,
    unsigned short* __restrict__ VT) {
  __shared__ __align__(16) unsigned short Al[128 * 64];   // 16 KB
  __shared__ __align__(16) unsigned short Bl[128 * 64];   // 16 KB
  const int lin = blockIdx.x;
  const int xcd = lin & 7, sblk = lin >> 3;       // sblk 0..95
  const int m0 = ((xcd & 3) * 8 + (sblk & 7)) * 128;
  const int n0g = ((xcd >> 2) * 12 + (sblk >> 3)) * 128;
  const int sel = n0g >> 10;
  const int tid = threadIdx.x;
  const int w = tid >> 6, lane = tid & 63;
  const int c = lane & 15, quad = lane >> 4;
  const int wm = (w & 1) * 64, wn = (w >> 1) * 64;

  f32x4 zero = {0.f, 0.f, 0.f, 0.f};
  f32x4 acc[4][4];
#pragma unroll
  for (int i = 0; i < 4; ++i)
#pragma unroll
    for (int j = 0; j < 4; ++j) acc[i][j] = zero;

  // staging: wave covers 8 rows per gld16 (8 lanes x 16B per row);
  // source column carries the chunk swizzle (attn K pattern).
  const int l8 = lane >> 3, p8 = lane & 7;
  const unsigned short* gA = Xb + (size_t)(m0 + w * 8 + l8) * DIMN + ((p8 ^ l8) * 8);
  const unsigned short* gB = Wb + (size_t)(n0g + w * 8 + l8) * DIMN + ((p8 ^ l8) * 8);
  unsigned short* lA = Al + (w * 8) * 64;
  unsigned short* lB = Bl + (w * 8) * 64;
  const int c7 = c & 7;

  for (int k0 = 0; k0 < DIMN; k0 += 64) {
    __syncthreads();
#pragma unroll
    for (int r = 0; r < 4; ++r) {
      gld16(gA + k0 + (size_t)(r * 32) * DIMN, lA + r * 32 * 64);
      gld16(gB + k0 + (size_t)(r * 32) * DIMN, lB + r * 32 * 64);
    }
    __syncthreads();
#pragma unroll
    for (int f = 0; f < 2; ++f) {
      const int rd = ((f * 4 + quad) ^ c7) * 8;
      s16x8 a[4], b[4];
#pragma unroll
      for (int i = 0; i < 4; ++i)
        a[i] = *(const s16x8*)&Al[(wm + i * 16 + c) * 64 + rd];
#pragma unroll
      for (int j = 0; j < 4; ++j)
        b[j] = *(const s16x8*)&Bl[(wn + j * 16 + c) * 64 + rd];
      if (sel != 2) {
#pragma unroll
        for (int i = 0; i < 4; ++i)
#pragma unroll
          for (int j = 0; j < 4; ++j)  // swapped -> C^T (4 consecutive d / lane)
            acc[i][j] = __builtin_amdgcn_mfma_f32_16x16x32_bf16(b[j], a[i], acc[i][j], 0, 0, 0);
      } else {
#pragma unroll
        for (int i = 0; i < 4; ++i)
#pragma unroll
          for (int j = 0; j < 4; ++j)  // normal (4 consecutive seq / lane)
            acc[i][j] = __builtin_amdgcn_mfma_f32_16x16x32_bf16(a[i], b[j], acc[i][j], 0, 0, 0);
      }
    }
  }

  const int n0 = n0g & 1023;
  if (sel != 2) {
    // C^T: row = n (d), col = seq. 8B packed stores, layout [B,H,L,D].
    unsigned short* Out = (sel == 0) ? Qb : Kb;
    const float scale = (sel == 0) ? QSCALE : 1.0f;
    const int bi = (m0 + wm) >> 11;
#pragma unroll
    for (int i = 0; i < 4; ++i) {
      const int li = (m0 + wm + i * 16 + c) & 2047;
#pragma unroll
      for (int j = 0; j < 4; ++j) {
        const int nq = n0 + wn + j * 16 + quad * 4;
        const int h = nq >> 6, d = nq & 63;
        uint2 st;
        st.x = packbf2(acc[i][j][0] * scale, acc[i][j][1] * scale);
        st.y = packbf2(acc[i][j][2] * scale, acc[i][j][3] * scale);
        *(uint2*)&Out[(((size_t)bi * NH + h) * LL + li) * HD + d] = st;
      }
    }
  } else {
    // normal C: row = seq, col = n (d). 8B packed stores, layout [B,H,D,L]
    // with vpos permutation per 128-seq group (keeps low 2 bits -> contiguous).
    const int bi = m0 >> 11;
    const int mlo = m0 & 2047;
#pragma unroll
    for (int i = 0; i < 4; ++i) {
      const int pos = mlo + vpos(wm + i * 16 + quad * 4);
#pragma unroll
      for (int j = 0; j < 4; ++j) {
        const int nv = n0 + wn + j * 16 + c;
        const int h = nv >> 6, d = nv & 63;
        uint2 st;
        st.x = packbf2(acc[i][j][0], acc[i][j][1]);
        st.y = packbf2(acc[i][j][2], acc[i][j][3]);
        *(uint2*)&VT[(((size_t)bi * NH + h) * HD + d) * LL + pos] = st;
      }
    }
  }
}

// ---------------- output projection, 128x128, BK=64, 2-phase ----------------
// grid 256 (1D, XCD-swizzled) = exactly 1 block/CU, ONE round (was 512/2).
// At 1 block/CU there is no co-residency to lose -> 2-phase dbuf (64 KB)
// hides load latency under compute. Swapped MFMA -> C^T frags -> float4
// coalesced fp32 stores. Per-XCD: B (Wo, 2MB) + A panel (1MB) fit L2.
__global__ __launch_bounds__(256) void gemm_o(
    const unsigned short* __restrict__ A, const unsigned short* __restrict__ Wob,
    float* __restrict__ Out) {
  __shared__ __align__(16) unsigned short Al[2][128 * 64];   // 32 KB
  __shared__ __align__(16) unsigned short Bl[2][128 * 64];   // 32 KB
  const int lin = blockIdx.x;
  const int xcd = lin & 7, sblk = lin >> 3;       // sblk 0..31
  const int m0 = (xcd * 4 + (sblk >> 3)) * 128;   // m-chunk 0..31
  const int n0 = (sblk & 7) * 128;                // n-chunk 0..7
  const int tid = threadIdx.x;
  const int w = tid >> 6, lane = tid & 63;
  const int c = lane & 15, quad = lane >> 4;
  const int wm = (w & 1) * 64, wn = (w >> 1) * 64;

  f32x4 zero = {0.f, 0.f, 0.f, 0.f};
  f32x4 acc[4][4];
#pragma unroll
  for (int i = 0; i < 4; ++i)
#pragma unroll
    for (int j = 0; j < 4; ++j) acc[i][j] = zero;

  const int l8 = lane >> 3, p8 = lane & 7;
  const unsigned short* gA = A + (size_t)(m0 + w * 8 + l8) * DIMN + ((p8 ^ l8) * 8);
  const unsigned short* gB = Wob + (size_t)(n0 + w * 8 + l8) * DIMN + ((p8 ^ l8) * 8);
  const int c7 = c & 7;

#define STAGEO(buf, k0)                                                       \
  do {                                                                        \
    unsigned short* lA_ = &Al[buf][(w * 8) * 64];                             \
    unsigned short* lB_ = &Bl[buf][(w * 8) * 64];                             \
    _Pragma("unroll")                                                         \
    for (int r = 0; r < 4; ++r) {                                             \
      gld16(gA + (k0) + (size_t)(r * 32) * DIMN, lA_ + r * 32 * 64);          \
      gld16(gB + (k0) + (size_t)(r * 32) * DIMN, lB_ + r * 32 * 64);          \
    }                                                                         \
  } while (0)

  STAGEO(0, 0);
  __syncthreads();

  for (int t = 0; t < 16; ++t) {
    if (t < 15) STAGEO((t + 1) & 1, (t + 1) * 64);
    const unsigned short* At = &Al[t & 1][0];
    const unsigned short* Bt = &Bl[t & 1][0];
#pragma unroll
    for (int f = 0; f < 2; ++f) {
      const int rd = ((f * 4 + quad) ^ c7) * 8;
      s16x8 a[4], b[4];
#pragma unroll
      for (int i = 0; i < 4; ++i)
        a[i] = *(const s16x8*)&At[(wm + i * 16 + c) * 64 + rd];
#pragma unroll
      for (int j = 0; j < 4; ++j)
        b[j] = *(const s16x8*)&Bt[(wn + j * 16 + c) * 64 + rd];
#pragma unroll
      for (int i = 0; i < 4; ++i)
#pragma unroll
        for (int j = 0; j < 4; ++j)  // swapped -> C^T: lane holds 4 consecutive n
          acc[i][j] = __builtin_amdgcn_mfma_f32_16x16x32_bf16(b[j], a[i], acc[i][j], 0, 0, 0);
    }
    __syncthreads();
  }
#undef STAGEO

  // C^T frags: seq = m0+wm+i*16+c, n = n0+wn+j*16+quad*4+(0..3) -> float4.
#pragma unroll
  for (int i = 0; i < 4; ++i) {
    const int mi = m0 + wm + i * 16 + c;
#pragma unroll
    for (int j = 0; j < 4; ++j) {
      const int nq = n0 + wn + j * 16 + quad * 4;
      *(f32x4*)&Out[(size_t)mi * DIMN + nq] = acc[i][j];
    }
  }
}

// ---------------- flash attention, in-block KV-split (unchanged R14) ----------
// 512 thr, 8 waves. half = w>>2: waves 0-3 do kv[0:1024), 4-7 kv[1024:2048),
// same 128 q-rows (each wave 2x16-row sets). KVBLK=64, dbuf 32KB/half ->
// 64KB/block -> 2 blocks/CU -> 4 waves/SIMD. LDS combine epilogue.
__global__ __launch_bounds__(512, 4) void attn9(
    const unsigned short* __restrict__ Qb, const unsigned short* __restrict__ Kb,
    const unsigned short* __restrict__ VT, unsigned short* __restrict__ AO) {
  __shared__ __align__(16) unsigned short Kl[2][2][64 * 64];   // 32 KB
  __shared__ __align__(16) unsigned short Vtl[2][2][64 * 64];  // 32 KB

  const int lin = blockIdx.x;
  const int xcd = lin & 7, sblk = lin >> 3;       // sblk 0..63
  const int bh = (sblk >> 4) * 8 + xcd;
  const int qi = sblk & 15;
  const int tid = threadIdx.x;
  const int w = tid >> 6, lane = tid & 63;
  const int half = w >> 2, wl = w & 3;
  const int c = lane & 15, quad = lane >> 4;
  const int qa = qi * 128 + wl * 16;    // set A rows [qa, qa+16)
  const int qbr = qa + 64;              // set B rows [qa+64, qa+80)

  const unsigned short* Qh = Qb + (size_t)bh * LL * HD;
  const unsigned short* Kh = Kb + (size_t)bh * LL * HD + (size_t)half * 1024 * HD;
  const unsigned short* Vh = VT + (size_t)bh * HD * LL + half * 1024;  // col offset

  s16x8 qA0 = *(const s16x8*)(Qh + (size_t)(qa + c) * HD + quad * 8);
  s16x8 qA1 = *(const s16x8*)(Qh + (size_t)(qa + c) * HD + 32 + quad * 8);
  s16x8 qB0 = *(const s16x8*)(Qh + (size_t)(qbr + c) * HD + quad * 8);
  s16x8 qB1 = *(const s16x8*)(Qh + (size_t)(qbr + c) * HD + 32 + quad * 8);

  f32x4 zero = {0.f, 0.f, 0.f, 0.f};
  f32x4 oA[4], oB[4];
  float lsumA = 0.f, lsumB = 0.f;
#pragma unroll
  for (int dc = 0; dc < 4; ++dc) { oA[dc] = zero; oB[dc] = zero; }

  // staging: within a half, wave wl covers K rows [wl*16,+16) and V rows
  // (d) [wl*16,+16). Rows are 64 shorts (128B), chunk-swizzle key row&7.
  const int l8 = lane >> 3, p8 = lane & 7;
  const unsigned short* gK = Kh + (size_t)(wl * 16 + l8) * HD + ((p8 ^ l8) * 8);
  const int vr = wl * 16 + l8;          // (vr&7)==l8, also for vr+8
  const unsigned short* gV = Vh + (size_t)vr * LL + ((p8 ^ l8) * 8);

  const int c7 = c & 7;
  const int kpa = (quad ^ c7) * 8;
  const int kpb = ((quad + 4) ^ c7) * 8;

#define STAGE(buf, kv)                                                        \
  do {                                                                        \
    unsigned short* lK_ = &Kl[half][buf][(wl * 16) * 64];                     \
    unsigned short* lV_ = &Vtl[half][buf][(wl * 16) * 64];                    \
    gld16(gK + (size_t)(kv) * HD, lK_);                                       \
    gld16(gK + (size_t)((kv) + 8) * HD, lK_ + 8 * 64);                        \
    gld16(gV + (kv), lV_);                                                    \
    gld16(gV + (size_t)8 * LL + (kv), lV_ + 8 * 64);                          \
  } while (0)

  STAGE(0, 0);

  for (int it = 0; it < 16; ++it) {
    __syncthreads();
    if (it + 1 < 16) STAGE((it + 1) & 1, (it + 1) * 64);
    const unsigned short* Kt = &Kl[half][it & 1][0];
    const unsigned short* Vt = &Vtl[half][it & 1][0];

    // QK^T: 64 kv x 16 q per set
    f32x4 sA[4], sB[4];
#pragma unroll
    for (int t4 = 0; t4 < 4; ++t4) {
      const unsigned short* kr = Kt + (t4 * 16 + c) * 64;
      s16x8 kfa = *(const s16x8*)(kr + kpa);
      s16x8 kfb = *(const s16x8*)(kr + kpb);
      sA[t4] = __builtin_amdgcn_mfma_f32_16x16x32_bf16(kfa, qA0, zero, 0, 0, 0);
      sA[t4] = __builtin_amdgcn_mfma_f32_16x16x32_bf16(kfb, qA1, sA[t4], 0, 0, 0);
      sB[t4] = __builtin_amdgcn_mfma_f32_16x16x32_bf16(kfa, qB0, zero, 0, 0, 0);
      sB[t4] = __builtin_amdgcn_mfma_f32_16x16x32_bf16(kfb, qB1, sB[t4], 0, 0, 0);
    }

    // softmax (no max-subtract; scores pre-scaled by log2(e)/8)
    float pA[4][4], pB[4][4];
    float a0 = 0.f, a1 = 0.f, b0 = 0.f, b1 = 0.f;
#pragma unroll
    for (int t4 = 0; t4 < 4; ++t4)
#pragma unroll
      for (int r = 0; r < 4; ++r) {
        float eA = xexp2(sA[t4][r]);
        float eB = xexp2(sB[t4][r]);
        pA[t4][r] = eA; pB[t4][r] = eB;
        if (t4 & 1) { a1 += eA; b1 += eB; } else { a0 += eA; b0 += eB; }
      }
    lsumA += a0 + a1; lsumB += b0 + b1;

    s16x8 pfA[2], pfB[2];
#pragma unroll
    for (int kh = 0; kh < 2; ++kh) {
      unsigned puA[4], puB[4];
      puA[0] = __builtin_amdgcn_perm(__float_as_uint(pA[2 * kh][1]),
                                     __float_as_uint(pA[2 * kh][0]), 0x07060302u);
      puA[1] = __builtin_amdgcn_perm(__float_as_uint(pA[2 * kh][3]),
                                     __float_as_uint(pA[2 * kh][2]), 0x07060302u);
      puA[2] = __builtin_amdgcn_perm(__float_as_uint(pA[2 * kh + 1][1]),
                                     __float_as_uint(pA[2 * kh + 1][0]), 0x07060302u);
      puA[3] = __builtin_amdgcn_perm(__float_as_uint(pA[2 * kh + 1][3]),
                                     __float_as_uint(pA[2 * kh + 1][2]), 0x07060302u);
      puB[0] = __builtin_amdgcn_perm(__float_as_uint(pB[2 * kh][1]),
                                     __float_as_uint(pB[2 * kh][0]), 0x07060302u);
      puB[1] = __builtin_amdgcn_perm(__float_as_uint(pB[2 * kh][3]),
                                     __float_as_uint(pB[2 * kh][2]), 0x07060302u);
      puB[2] = __builtin_amdgcn_perm(__float_as_uint(pB[2 * kh + 1][1]),
                                     __float_as_uint(pB[2 * kh + 1][0]), 0x07060302u);
      puB[3] = __builtin_amdgcn_perm(__float_as_uint(pB[2 * kh + 1][3]),
                                     __float_as_uint(pB[2 * kh + 1][2]), 0x07060302u);
      pfA[kh] = *(const s16x8*)puA;
      pfB[kh] = *(const s16x8*)puB;
    }

    // PV: kk slots 0..1 (64 kv)
#pragma unroll
    for (int kh = 0; kh < 2; ++kh) {
#pragma unroll
      for (int dc = 0; dc < 4; ++dc) {
        s16x8 vf = *(const s16x8*)(Vt + (dc * 16 + c) * 64 +
                                   (((kh * 4 + quad) ^ c7) * 8));
        oA[dc] = __builtin_amdgcn_mfma_f32_16x16x32_bf16(vf, pfA[kh], oA[dc], 0, 0, 0);
        oB[dc] = __builtin_amdgcn_mfma_f32_16x16x32_bf16(vf, pfB[kh], oB[dc], 0, 0, 0);
      }
    }
  }
#undef STAGE

  // ---- combine the two kv-halves via LDS (reuse K/V buffers) ----
  float lA = lsumA;
  lA += __shfl_xor(lA, 16);
  lA += __shfl_xor(lA, 32);
  float lB = lsumB;
  lB += __shfl_xor(lB, 16);
  lB += __shfl_xor(lB, 32);

  f32x4* ob4 = (f32x4*)&Kl[0][0][0];    // 32 KB: [wl*2+set][dc][lane]
  float* lb = (float*)&Vtl[0][0][0];    // [wl*2+set][lane]

  __syncthreads();
  if (half == 1) {
#pragma unroll
    for (int dc = 0; dc < 4; ++dc) {
      ob4[((wl * 2 + 0) * 4 + dc) * 64 + lane] = oA[dc];
      ob4[((wl * 2 + 1) * 4 + dc) * 64 + lane] = oB[dc];
    }
    lb[(wl * 2 + 0) * 64 + lane] = lA;
    lb[(wl * 2 + 1) * 64 + lane] = lB;
  }
  __syncthreads();
  if (half == 0) {
    lA += lb[(wl * 2 + 0) * 64 + lane];
    lB += lb[(wl * 2 + 1) * 64 + lane];
    float invA = 1.0f / lA;
    float invB = 1.0f / lB;
    const int bi = bh >> 4, h = bh & 15;
    unsigned short* dstA = AO + ((size_t)bi * LL + qa + c) * DIMN + h * HD + quad * 4;
    unsigned short* dstB = AO + ((size_t)bi * LL + qbr + c) * DIMN + h * HD + quad * 4;
#pragma unroll
    for (int dc = 0; dc < 4; ++dc) {
      f32x4 sa = oA[dc] + ob4[((wl * 2 + 0) * 4 + dc) * 64 + lane];
      f32x4 sb = oB[dc] + ob4[((wl * 2 + 1) * 4 + dc) * 64 + lane];
      uint2 stA, stB;
      stA.x = packbf2(sa[0] * invA, sa[1] * invA);
      stA.y = packbf2(sa[2] * invA, sa[3] * invA);
      stB.x = packbf2(sb[0] * invB, sb[1] * invB);
      stB.y = packbf2(sb[2] * invB, sb[3] * invB);
      *(uint2*)(dstA + dc * 16) = stA;
      *(uint2*)(dstB + dc * 16) = stB;
    }
  }
}

// ---------------- fp32 fallback path (1-wave GEMMs), ws < 48 MiB ----------------
__global__ __launch_bounds__(64) void qkv_proj_f(
    const float* __restrict__ X, const float* __restrict__ Wq,
    const float* __restrict__ Wk, const float* __restrict__ Wv,
    unsigned short* __restrict__ Qb, unsigned short* __restrict__ Kb,
    unsigned short* __restrict__ VT) {
  const int m0 = blockIdx.x * 64;
  const int n0g = blockIdx.y * 64;
  const int sel = n0g >> 10;
  const int n0 = n0g & 1023;
  const float* W = (sel == 0) ? Wq : (sel == 1) ? Wk : Wv;
  const int lane = threadIdx.x;
  const int c = lane & 15, quad = lane >> 4;

  f32x4 zero = {0.f, 0.f, 0.f, 0.f};
  f32x4 acc[4][4];
#pragma unroll
  for (int i = 0; i < 4; ++i)
#pragma unroll
    for (int j = 0; j < 4; ++j) acc[i][j] = zero;

  const float* ab = X + (size_t)(m0 + c) * DIMN + quad * 8;
  const float* bb = W + (size_t)(n0 + c) * DIMN + quad * 8;

  for (int k0 = 0; k0 < DIMN; k0 += 32) {
    s16x8 a[4], b[4];
#pragma unroll
    for (int i = 0; i < 4; ++i) {
      const float* pp = ab + i * 16 * DIMN + k0;
      a[i] = cvt8(*(const float4*)pp, *(const float4*)(pp + 4));
    }
#pragma unroll
    for (int j = 0; j < 4; ++j) {
      const float* pp = bb + j * 16 * DIMN + k0;
      b[j] = cvt8(*(const float4*)pp, *(const float4*)(pp + 4));
    }
    if (sel != 2) {
#pragma unroll
      for (int i = 0; i < 4; ++i)
#pragma unroll
        for (int j = 0; j < 4; ++j)
          acc[i][j] = __builtin_amdgcn_mfma_f32_16x16x32_bf16(a[i], b[j], acc[i][j], 0, 0, 0);
    } else {
#pragma unroll
      for (int i = 0; i < 4; ++i)
#pragma unroll
        for (int j = 0; j < 4; ++j)
          acc[i][j] = __builtin_amdgcn_mfma_f32_16x16x32_bf16(b[j], a[i], acc[i][j], 0, 0, 0);
    }
  }

  if (sel != 2) {
    unsigned short* Out = (sel == 0) ? Qb : Kb;
    const float scale = (sel == 0) ? QSCALE : 1.0f;
#pragma unroll
    for (int i = 0; i < 4; ++i)
#pragma unroll
      for (int j = 0; j < 4; ++j)
#pragma unroll
        for (int r = 0; r < 4; ++r) {
          int row = m0 + i * 16 + quad * 4 + r;
          int nl = n0 + j * 16 + c;
          int bi = row >> 11, li = row & 2047;
          int h = nl >> 6, d = nl & 63;
          Out[(((size_t)bi * NH + h) * LL + li) * HD + d] = f2bf(acc[i][j][r] * scale);
        }
  } else {
#pragma unroll
    for (int i = 0; i < 4; ++i) {
#pragma unroll
      for (int j = 0; j < 4; ++j)
#pragma unroll
        for (int r = 0; r < 4; ++r) {
          int n = n0 + j * 16 + quad * 4 + r;
          int s128 = (m0 & 64) + i * 16 + c;
          int m = (m0 & ~127) + vpos(s128);
          int h = n >> 6, d = n & 63;
          int bi = m0 >> 11;
          VT[(((size_t)bi * NH + h) * HD + d) * LL + (m & 2047)] = f2bf(acc[i][j][r]);
        }
    }
  }
}

__global__ __launch_bounds__(64) void o_proj_f(
    const unsigned short* __restrict__ A, const float* __restrict__ Wo,
    float* __restrict__ Out) {
  const int m0 = blockIdx.x * 64, n0 = blockIdx.y * 64;
  const int lane = threadIdx.x;
  const int c = lane & 15, quad = lane >> 4;

  f32x4 zero = {0.f, 0.f, 0.f, 0.f};
  f32x4 acc[4][4];
#pragma unroll
  for (int i = 0; i < 4; ++i)
#pragma unroll
    for (int j = 0; j < 4; ++j) acc[i][j] = zero;

  const unsigned short* ab = A + (size_t)(m0 + c) * DIMN + quad * 8;
  const float* bb = Wo + (size_t)(n0 + c) * DIMN + quad * 8;

  for (int k0 = 0; k0 < DIMN; k0 += 32) {
    s16x8 a[4], b[4];
#pragma unroll
    for (int i = 0; i < 4; ++i) a[i] = *(const s16x8*)(ab + i * 16 * DIMN + k0);
#pragma unroll
    for (int j = 0; j < 4; ++j) {
      const float* pp = bb + j * 16 * DIMN + k0;
      b[j] = cvt8(*(const float4*)pp, *(const float4*)(pp + 4));
    }
#pragma unroll
    for (int i = 0; i < 4; ++i)
#pragma unroll
      for (int j = 0; j < 4; ++j)
        acc[i][j] = __builtin_amdgcn_mfma_f32_16x16x32_bf16(a[i], b[j], acc[i][j], 0, 0, 0);
  }

#pragma unroll
  for (int i = 0; i < 4; ++i)
#pragma unroll
    for (int j = 0; j < 4; ++j)
#pragma unroll
      for (int r = 0; r < 4; ++r)
        Out[(size_t)(m0 + i * 16 + quad * 4 + r) * DIMN + n0 + j * 16 + c] = acc[i][j][r];
}

extern "C" void kernel_launch(void* const* d_in, const int* in_sizes, int n_in,
                              void* d_out, int out_size, void* d_ws, size_t ws_size,
                              hipStream_t stream) {
  const float* X = (const float*)d_in[0];
  const float* Wq = (const float*)d_in[1];
  const float* Wk = (const float*)d_in[2];
  const float* Wv = (const float*)d_in[3];
  const float* Wo = (const float*)d_in[4];
  float* Out = (float*)d_out;

  const size_t M1 = (size_t)1 << 20;
  unsigned short* ws16 = (unsigned short*)d_ws;

  if (ws_size >= (size_t)48 * 1024 * 1024) {
    unsigned short* Xb = ws16;            // 4M elems
    unsigned short* Wb = ws16 + 4 * M1;   // 4 x 1M (Wq,Wk,Wv,Wo contiguous)
    unsigned short* Qb = ws16 + 8 * M1;
    unsigned short* Kb = ws16 + 12 * M1;
    unsigned short* VT = ws16 + 16 * M1;
    unsigned short* AO = ws16 + 20 * M1;
    cvt_all<<<4096, 256, 0, stream>>>(X, Wq, Wk, Wv, Wo, ws16);
    gemm_qkv<<<768, 256, 0, stream>>>(Xb, Wb, Qb, Kb, VT);
    attn9<<<512, 512, 0, stream>>>(Qb, Kb, VT, AO);
    gemm_o<<<256, 256, 0, stream>>>(AO, Wb + 3 * M1, Out);
  } else {
    unsigned short* Qb = ws16;
    unsigned short* Kb = ws16 + 4 * M1;
    unsigned short* VT = ws16 + 8 * M1;
    unsigned short* AO = ws16 + 12 * M1;
    qkv_proj_f<<<dim3(64, 48), 64, 0, stream>>>(X, Wq, Wk, Wv, Qb, Kb, VT);
    attn9<<<512, 512, 0, stream>>>(Qb, Kb, VT, AO);
    o_proj_f<<<dim3(64, 16), 64, 0, stream>>>(AO, Wo, Out);
  }
}

// Round 6
// 175.305 us; speedup vs baseline: 1.0387x; 1.0387x over previous
//
#include <hip/hip_runtime.h>

// MultiHeadAttention: out = softmax((XWq^T)(XWk^T)^T / 8) (XWv^T) Wo^T
// B=2, L=2048, DIM=1024, H=16, D=64. fp32 in/out, bf16 MFMA compute.
//
// R17: (a) gemm_o reverted to R14 proven form (512 blocks, 24KB, 2/CU).
//      (b) attn9 -> attn10. attn9's time closes as SERIALIZED pipe-sum:
//      LDS-read 20.5 + stage 3.4 + MFMA 16.5 + VALU 6 = 46.4us (measured).
//      Lever = shrink dominant term: 4 q-sets/wave (64 q rows) -> each K/V
//      LDS fragment feeds 4 MFMAs (was 2) -> per-CU ds_reads halve.
//      Block 8 waves covers 256 q rows; grid 256 (1 block/CU); kv-halves
//      + 2-pass LDS combine. Staging/swizzles byte-identical to attn9.

#define DIMN 1024
#define NH 16
#define HD 64
#define BB 2
#define LL 2048

typedef float f32x4 __attribute__((ext_vector_type(4)));
typedef short s16x8 __attribute__((ext_vector_type(8)));

#define QSCALE 0.18033688011112042f  // log2(e)/8, folds softmax exp2 domain

static __device__ __forceinline__ unsigned short f2bf(float f) {
  unsigned u = __float_as_uint(f);
  u += 0x7fffu + ((u >> 16) & 1u);   // RNE
  return (unsigned short)(u >> 16);
}
static __device__ __forceinline__ unsigned packbf2(float lo, float hi) {
  return (unsigned)f2bf(lo) | ((unsigned)f2bf(hi) << 16);
}
static __device__ __forceinline__ float xexp2(float x) {
#if __has_builtin(__builtin_amdgcn_exp2f)
  return __builtin_amdgcn_exp2f(x);
#else
  return exp2f(x);
#endif
}
static __device__ __forceinline__ s16x8 cvt8(float4 a, float4 b) {
  s16x8 r;
  r[0] = (short)f2bf(a.x); r[1] = (short)f2bf(a.y);
  r[2] = (short)f2bf(a.z); r[3] = (short)f2bf(a.w);
  r[4] = (short)f2bf(b.x); r[5] = (short)f2bf(b.y);
  r[6] = (short)f2bf(b.z); r[7] = (short)f2bf(b.w);
  return r;
}
// async global->LDS, 16B/lane; LDS dest is wave-uniform base + lane*16
static __device__ __forceinline__ void gld16(const unsigned short* g,
                                             unsigned short* l) {
#if __has_builtin(__builtin_amdgcn_global_load_lds)
  __builtin_amdgcn_global_load_lds(
      (const __attribute__((address_space(1))) void*)g,
      (__attribute__((address_space(3))) void*)l, 16, 0, 0);
#else
  ((uint4*)l)[threadIdx.x & 63] = ((const uint4*)g)[0];
#endif
}

// V storage permutation within each 128-seq group (bits of s):
// pos = b6*64 + b5*32 + (bits3:2)*8 + bit4*4 + bits1:0  — keeps low 2 bits.
// Maps 64-aligned windows onto themselves -> kv-half/tile decomposition safe.
static __device__ __forceinline__ int vpos(int s128) {
  return (s128 & 0x60) | ((s128 & 0x0C) << 1) | ((s128 & 0x10) >> 2) | (s128 & 3);
}

// ---------------- fp32 -> bf16 pre-convert (X + 4 weights) ----------------
__global__ __launch_bounds__(256) void cvt_all(
    const float* __restrict__ X, const float* __restrict__ Wq,
    const float* __restrict__ Wk, const float* __restrict__ Wv,
    const float* __restrict__ Wo, unsigned short* __restrict__ out) {
  const int blk = blockIdx.x;
  const float* src;
  unsigned short* dst;
  size_t off;
  if (blk < 2048) {
    src = X; dst = out; off = (size_t)blk * 2048;
  } else {
    int s = (blk - 2048) >> 9;
    src = (s == 0) ? Wq : (s == 1) ? Wk : (s == 2) ? Wv : Wo;
    dst = out + ((size_t)1 << 22) + (size_t)s * (1u << 20);
    off = (size_t)((blk - 2048) & 511) * 2048;
  }
  size_t i = off + (size_t)threadIdx.x * 8;
  float4 v0 = *(const float4*)(src + i);
  float4 v1 = *(const float4*)(src + i + 4);
  uint4 o;
  o.x = packbf2(v0.x, v0.y); o.y = packbf2(v0.z, v0.w);
  o.z = packbf2(v1.x, v1.y); o.w = packbf2(v1.z, v1.w);
  *(uint4*)(dst + i) = o;
}

// ---------------- fused QKV projection, 128x128, BK=64 (R11 form) ----------
// grid 768 (1D, XCD-swizzled). Rows in LDS are 64 shorts (128 B), chunk-
// swizzled: phys slot p of row r holds logical chunk p ^ (r&7).
// Single-buffer 32KB -> 3 blocks/CU co-resident (TLP hides the drain).
__global__ __launch_bounds__(256) void gemm_qkv(
    const unsigned short* __restrict__ Xb, const unsigned short* __restrict__ Wb,
    unsigned short* __restrict__ Qb, unsigned short* __restrict__ Kb,
    unsigned short* __restrict__ VT) {
  __shared__ __align__(16) unsigned short Al[128 * 64];   // 16 KB
  __shared__ __align__(16) unsigned short Bl[128 * 64];   // 16 KB
  const int lin = blockIdx.x;
  const int xcd = lin & 7, sblk = lin >> 3;       // sblk 0..95
  const int m0 = ((xcd & 3) * 8 + (sblk & 7)) * 128;
  const int n0g = ((xcd >> 2) * 12 + (sblk >> 3)) * 128;
  const int sel = n0g >> 10;
  const int tid = threadIdx.x;
  const int w = tid >> 6, lane = tid & 63;
  const int c = lane & 15, quad = lane >> 4;
  const int wm = (w & 1) * 64, wn = (w >> 1) * 64;

  f32x4 zero = {0.f, 0.f, 0.f, 0.f};
  f32x4 acc[4][4];
#pragma unroll
  for (int i = 0; i < 4; ++i)
#pragma unroll
    for (int j = 0; j < 4; ++j) acc[i][j] = zero;

  const int l8 = lane >> 3, p8 = lane & 7;
  const unsigned short* gA = Xb + (size_t)(m0 + w * 8 + l8) * DIMN + ((p8 ^ l8) * 8);
  const unsigned short* gB = Wb + (size_t)(n0g + w * 8 + l8) * DIMN + ((p8 ^ l8) * 8);
  unsigned short* lA = Al + (w * 8) * 64;
  unsigned short* lB = Bl + (w * 8) * 64;
  const int c7 = c & 7;

  for (int k0 = 0; k0 < DIMN; k0 += 64) {
    __syncthreads();
#pragma unroll
    for (int r = 0; r < 4; ++r) {
      gld16(gA + k0 + (size_t)(r * 32) * DIMN, lA + r * 32 * 64);
      gld16(gB + k0 + (size_t)(r * 32) * DIMN, lB + r * 32 * 64);
    }
    __syncthreads();
#pragma unroll
    for (int f = 0; f < 2; ++f) {
      const int rd = ((f * 4 + quad) ^ c7) * 8;
      s16x8 a[4], b[4];
#pragma unroll
      for (int i = 0; i < 4; ++i)
        a[i] = *(const s16x8*)&Al[(wm + i * 16 + c) * 64 + rd];
#pragma unroll
      for (int j = 0; j < 4; ++j)
        b[j] = *(const s16x8*)&Bl[(wn + j * 16 + c) * 64 + rd];
      if (sel != 2) {
#pragma unroll
        for (int i = 0; i < 4; ++i)
#pragma unroll
          for (int j = 0; j < 4; ++j)  // swapped -> C^T (4 consecutive d / lane)
            acc[i][j] = __builtin_amdgcn_mfma_f32_16x16x32_bf16(b[j], a[i], acc[i][j], 0, 0, 0);
      } else {
#pragma unroll
        for (int i = 0; i < 4; ++i)
#pragma unroll
          for (int j = 0; j < 4; ++j)  // normal (4 consecutive seq / lane)
            acc[i][j] = __builtin_amdgcn_mfma_f32_16x16x32_bf16(a[i], b[j], acc[i][j], 0, 0, 0);
      }
    }
  }

  const int n0 = n0g & 1023;
  if (sel != 2) {
    // C^T: row = n (d), col = seq. 8B packed stores, layout [B,H,L,D].
    unsigned short* Out = (sel == 0) ? Qb : Kb;
    const float scale = (sel == 0) ? QSCALE : 1.0f;
    const int bi = (m0 + wm) >> 11;
#pragma unroll
    for (int i = 0; i < 4; ++i) {
      const int li = (m0 + wm + i * 16 + c) & 2047;
#pragma unroll
      for (int j = 0; j < 4; ++j) {
        const int nq = n0 + wn + j * 16 + quad * 4;
        const int h = nq >> 6, d = nq & 63;
        uint2 st;
        st.x = packbf2(acc[i][j][0] * scale, acc[i][j][1] * scale);
        st.y = packbf2(acc[i][j][2] * scale, acc[i][j][3] * scale);
        *(uint2*)&Out[(((size_t)bi * NH + h) * LL + li) * HD + d] = st;
      }
    }
  } else {
    // normal C: row = seq, col = n (d). 8B packed stores, layout [B,H,D,L]
    // with vpos permutation per 128-seq group (keeps low 2 bits -> contiguous).
    const int bi = m0 >> 11;
    const int mlo = m0 & 2047;
#pragma unroll
    for (int i = 0; i < 4; ++i) {
      const int pos = mlo + vpos(wm + i * 16 + quad * 4);
#pragma unroll
      for (int j = 0; j < 4; ++j) {
        const int nv = n0 + wn + j * 16 + c;
        const int h = nv >> 6, d = nv & 63;
        uint2 st;
        st.x = packbf2(acc[i][j][0], acc[i][j][1]);
        st.y = packbf2(acc[i][j][2], acc[i][j][3]);
        *(uint2*)&VT[(((size_t)bi * NH + h) * HD + d) * LL + pos] = st;
      }
    }
  }
}

// ---------------- output projection, 128x64, BK=64 (R14 form) ----------------
// grid 512 (1D, XCD-swizzled). Same swizzled 64-short-row LDS tiles.
__global__ __launch_bounds__(256) void gemm_o(
    const unsigned short* __restrict__ A, const unsigned short* __restrict__ Wob,
    float* __restrict__ Out) {
  __shared__ __align__(16) unsigned short Al[128 * 64];   // 16 KB
  __shared__ __align__(16) unsigned short Bl[64 * 64];    // 8 KB
  const int lin = blockIdx.x;
  const int xcd = lin & 7, sblk = lin >> 3;       // sblk 0..63
  const int m0 = ((sblk >> 4) * 8 + xcd) * 128;
  const int n0 = (sblk & 15) * 64;
  const int tid = threadIdx.x;
  const int w = tid >> 6, lane = tid & 63;
  const int c = lane & 15, quad = lane >> 4;
  const int wm = (w & 1) * 64, wn = (w >> 1) * 32;

  f32x4 zero = {0.f, 0.f, 0.f, 0.f};
  f32x4 acc[4][2];
#pragma unroll
  for (int i = 0; i < 4; ++i)
#pragma unroll
    for (int j = 0; j < 2; ++j) acc[i][j] = zero;

  const int l8 = lane >> 3, p8 = lane & 7;
  const unsigned short* gA = A + (size_t)(m0 + w * 8 + l8) * DIMN + ((p8 ^ l8) * 8);
  const unsigned short* gB = Wob + (size_t)(n0 + w * 8 + l8) * DIMN + ((p8 ^ l8) * 8);
  unsigned short* lA = Al + (w * 8) * 64;
  unsigned short* lB = Bl + (w * 8) * 64;
  const int c7 = c & 7;

  for (int k0 = 0; k0 < DIMN; k0 += 64) {
    __syncthreads();
#pragma unroll
    for (int r = 0; r < 4; ++r)
      gld16(gA + k0 + (size_t)(r * 32) * DIMN, lA + r * 32 * 64);
#pragma unroll
    for (int r = 0; r < 2; ++r)
      gld16(gB + k0 + (size_t)(r * 32) * DIMN, lB + r * 32 * 64);
    __syncthreads();
#pragma unroll
    for (int f = 0; f < 2; ++f) {
      const int rd = ((f * 4 + quad) ^ c7) * 8;
      s16x8 a[4], b[2];
#pragma unroll
      for (int i = 0; i < 4; ++i)
        a[i] = *(const s16x8*)&Al[(wm + i * 16 + c) * 64 + rd];
#pragma unroll
      for (int j = 0; j < 2; ++j)
        b[j] = *(const s16x8*)&Bl[(wn + j * 16 + c) * 64 + rd];
#pragma unroll
      for (int i = 0; i < 4; ++i)
#pragma unroll
        for (int j = 0; j < 2; ++j)
          acc[i][j] = __builtin_amdgcn_mfma_f32_16x16x32_bf16(a[i], b[j], acc[i][j], 0, 0, 0);
    }
  }

#pragma unroll
  for (int i = 0; i < 4; ++i)
#pragma unroll
    for (int j = 0; j < 2; ++j)
#pragma unroll
      for (int r = 0; r < 4; ++r)
        Out[(size_t)(m0 + wm + i * 16 + quad * 4 + r) * DIMN + n0 + wn + j * 16 + c] =
            acc[i][j][r];
}

// ---------------- flash attention, 4 q-sets/wave, kv-half split ----------------
// 512 thr, 8 waves: half = w>>2 (kv halves), wl = w&3. Each wave: 4 sets of
// 16 q rows (q0 + s*64), half the kv. Block covers 256 q rows; grid 256 =
// bh(32) x qblk(8), XCD-swizzled (4 bh per XCD -> K/V L2-resident).
// Per iter/wave: 16 ds_read_b128 feed 64 MFMA (4:1). 2-pass LDS combine.
__global__ __launch_bounds__(512) void attn10(
    const unsigned short* __restrict__ Qb, const unsigned short* __restrict__ Kb,
    const unsigned short* __restrict__ VT, unsigned short* __restrict__ AO) {
  __shared__ __align__(16) unsigned short Kl[2][2][64 * 64];   // [half][buf] 32 KB
  __shared__ __align__(16) unsigned short Vtl[2][2][64 * 64];  // 32 KB

  const int lin = blockIdx.x;
  const int xcd = lin & 7, sblk = lin >> 3;       // sblk 0..31
  const int bh = (sblk >> 3) * 8 + xcd;           // 4 bh per XCD
  const int qblk = sblk & 7;                      // 8 q-blocks of 256 rows
  const int tid = threadIdx.x;
  const int w = tid >> 6, lane = tid & 63;
  const int half = w >> 2, wl = w & 3;
  const int c = lane & 15, quad = lane >> 4;
  const int q0 = qblk * 256 + wl * 16;            // set s rows: q0 + s*64 + [0,16)

  const unsigned short* Qh = Qb + (size_t)bh * LL * HD;
  const unsigned short* Kh = Kb + (size_t)bh * LL * HD + (size_t)half * 1024 * HD;
  const unsigned short* Vh = VT + (size_t)bh * HD * LL + half * 1024;  // col offset

  s16x8 qf[4][2];
#pragma unroll
  for (int s = 0; s < 4; ++s) {
    qf[s][0] = *(const s16x8*)(Qh + (size_t)(q0 + s * 64 + c) * HD + quad * 8);
    qf[s][1] = *(const s16x8*)(Qh + (size_t)(q0 + s * 64 + c) * HD + 32 + quad * 8);
  }

  f32x4 zero = {0.f, 0.f, 0.f, 0.f};
  f32x4 o[4][4];          // [set][dc]
  float lsum[4] = {0.f, 0.f, 0.f, 0.f};
#pragma unroll
  for (int s = 0; s < 4; ++s)
#pragma unroll
    for (int dc = 0; dc < 4; ++dc) o[s][dc] = zero;

  // staging (identical to attn9): within a half, wave wl covers K rows
  // [wl*16,+16) and V d-rows [wl*16,+16); rows 64 shorts, chunk-swz key row&7.
  const int l8 = lane >> 3, p8 = lane & 7;
  const unsigned short* gK = Kh + (size_t)(wl * 16 + l8) * HD + ((p8 ^ l8) * 8);
  const int vr = wl * 16 + l8;
  const unsigned short* gV = Vh + (size_t)vr * LL + ((p8 ^ l8) * 8);

  const int c7 = c & 7;
  const int kpa = (quad ^ c7) * 8;
  const int kpb = ((quad + 4) ^ c7) * 8;

#define STAGE(buf, kv)                                                        \
  do {                                                                        \
    unsigned short* lK_ = &Kl[half][buf][(wl * 16) * 64];                     \
    unsigned short* lV_ = &Vtl[half][buf][(wl * 16) * 64];                    \
    gld16(gK + (size_t)(kv) * HD, lK_);                                       \
    gld16(gK + (size_t)((kv) + 8) * HD, lK_ + 8 * 64);                        \
    gld16(gV + (kv), lV_);                                                    \
    gld16(gV + (size_t)8 * LL + (kv), lV_ + 8 * 64);                          \
  } while (0)

  STAGE(0, 0);

  for (int it = 0; it < 16; ++it) {
    __syncthreads();
    if (it + 1 < 16) STAGE((it + 1) & 1, (it + 1) * 64);
    const unsigned short* Kt = &Kl[half][it & 1][0];
    const unsigned short* Vt = &Vtl[half][it & 1][0];

    // K fragments once -> reused by all 4 sets
    s16x8 kf[4][2];
#pragma unroll
    for (int t4 = 0; t4 < 4; ++t4) {
      const unsigned short* kr = Kt + (t4 * 16 + c) * 64;
      kf[t4][0] = *(const s16x8*)(kr + kpa);
      kf[t4][1] = *(const s16x8*)(kr + kpb);
    }

    s16x8 pf[4][2];
#pragma unroll
    for (int s = 0; s < 4; ++s) {
      f32x4 sc[4];
#pragma unroll
      for (int t4 = 0; t4 < 4; ++t4) {
        sc[t4] = __builtin_amdgcn_mfma_f32_16x16x32_bf16(kf[t4][0], qf[s][0], zero, 0, 0, 0);
        sc[t4] = __builtin_amdgcn_mfma_f32_16x16x32_bf16(kf[t4][1], qf[s][1], sc[t4], 0, 0, 0);
      }
      // softmax (no max-subtract; scores pre-scaled by log2(e)/8)
      float p[4][4];
      float a0 = 0.f, a1 = 0.f;
#pragma unroll
      for (int t4 = 0; t4 < 4; ++t4)
#pragma unroll
        for (int r = 0; r < 4; ++r) {
          float e = xexp2(sc[t4][r]);
          p[t4][r] = e;
          if (t4 & 1) a1 += e; else a0 += e;
        }
      lsum[s] += a0 + a1;
#pragma unroll
      for (int kh = 0; kh < 2; ++kh) {
        unsigned pu[4];
        pu[0] = __builtin_amdgcn_perm(__float_as_uint(p[2 * kh][1]),
                                      __float_as_uint(p[2 * kh][0]), 0x07060302u);
        pu[1] = __builtin_amdgcn_perm(__float_as_uint(p[2 * kh][3]),
                                      __float_as_uint(p[2 * kh][2]), 0x07060302u);
        pu[2] = __builtin_amdgcn_perm(__float_as_uint(p[2 * kh + 1][1]),
                                      __float_as_uint(p[2 * kh + 1][0]), 0x07060302u);
        pu[3] = __builtin_amdgcn_perm(__float_as_uint(p[2 * kh + 1][3]),
                                      __float_as_uint(p[2 * kh + 1][2]), 0x07060302u);
        pf[s][kh] = *(const s16x8*)pu;
      }
    }

    // PV: each vf read feeds all 4 sets
#pragma unroll
    for (int kh = 0; kh < 2; ++kh) {
#pragma unroll
      for (int dc = 0; dc < 4; ++dc) {
        s16x8 vf = *(const s16x8*)(Vt + (dc * 16 + c) * 64 +
                                   (((kh * 4 + quad) ^ c7) * 8));
#pragma unroll
        for (int s = 0; s < 4; ++s)
          o[s][dc] = __builtin_amdgcn_mfma_f32_16x16x32_bf16(vf, pf[s][kh], o[s][dc], 0, 0, 0);
      }
    }
  }
#undef STAGE

  // ---- combine the two kv-halves via LDS, 2 passes of 2 sets ----
#pragma unroll
  for (int s = 0; s < 4; ++s) {
    lsum[s] += __shfl_xor(lsum[s], 16);
    lsum[s] += __shfl_xor(lsum[s], 32);
  }

  f32x4* ob4 = (f32x4*)&Kl[0][0][0];    // 32 KB: [(wl*2+sp)*4+dc][lane]
  float* lb = (float*)&Vtl[0][0][0];    // [(wl*2+sp)][lane]
  const int bi = bh >> 4, h = bh & 15;

#pragma unroll
  for (int pass = 0; pass < 2; ++pass) {
    __syncthreads();
    if (half == 1) {
#pragma unroll
      for (int sp = 0; sp < 2; ++sp) {
        const int s = pass * 2 + sp;
#pragma unroll
        for (int dc = 0; dc < 4; ++dc)
          ob4[((wl * 2 + sp) * 4 + dc) * 64 + lane] = o[s][dc];
        lb[(wl * 2 + sp) * 64 + lane] = lsum[s];
      }
    }
    __syncthreads();
    if (half == 0) {
#pragma unroll
      for (int sp = 0; sp < 2; ++sp) {
        const int s = pass * 2 + sp;
        const float l = lsum[s] + lb[(wl * 2 + sp) * 64 + lane];
        const float inv = 1.0f / l;
        unsigned short* dst =
            AO + ((size_t)bi * LL + q0 + s * 64 + c) * DIMN + h * HD + quad * 4;
#pragma unroll
        for (int dc = 0; dc < 4; ++dc) {
          f32x4 sum = o[s][dc] + ob4[((wl * 2 + sp) * 4 + dc) * 64 + lane];
          uint2 st;
          st.x = packbf2(sum[0] * inv, sum[1] * inv);
          st.y = packbf2(sum[2] * inv, sum[3] * inv);
          *(uint2*)(dst + dc * 16) = st;
        }
      }
    }
  }
}

// ---------------- fp32 fallback path (1-wave GEMMs), ws < 48 MiB ----------------
__global__ __launch_bounds__(64) void qkv_proj_f(
    const float* __restrict__ X, const float* __restrict__ Wq,
    const float* __restrict__ Wk, const float* __restrict__ Wv,
    unsigned short* __restrict__ Qb, unsigned short* __restrict__ Kb,
    unsigned short* __restrict__ VT) {
  const int m0 = blockIdx.x * 64;
  const int n0g = blockIdx.y * 64;
  const int sel = n0g >> 10;
  const int n0 = n0g & 1023;
  const float* W = (sel == 0) ? Wq : (sel == 1) ? Wk : Wv;
  const int lane = threadIdx.x;
  const int c = lane & 15, quad = lane >> 4;

  f32x4 zero = {0.f, 0.f, 0.f, 0.f};
  f32x4 acc[4][4];
#pragma unroll
  for (int i = 0; i < 4; ++i)
#pragma unroll
    for (int j = 0; j < 4; ++j) acc[i][j] = zero;

  const float* ab = X + (size_t)(m0 + c) * DIMN + quad * 8;
  const float* bb = W + (size_t)(n0 + c) * DIMN + quad * 8;

  for (int k0 = 0; k0 < DIMN; k0 += 32) {
    s16x8 a[4], b[4];
#pragma unroll
    for (int i = 0; i < 4; ++i) {
      const float* pp = ab + i * 16 * DIMN + k0;
      a[i] = cvt8(*(const float4*)pp, *(const float4*)(pp + 4));
    }
#pragma unroll
    for (int j = 0; j < 4; ++j) {
      const float* pp = bb + j * 16 * DIMN + k0;
      b[j] = cvt8(*(const float4*)pp, *(const float4*)(pp + 4));
    }
    if (sel != 2) {
#pragma unroll
      for (int i = 0; i < 4; ++i)
#pragma unroll
        for (int j = 0; j < 4; ++j)
          acc[i][j] = __builtin_amdgcn_mfma_f32_16x16x32_bf16(a[i], b[j], acc[i][j], 0, 0, 0);
    } else {
#pragma unroll
      for (int i = 0; i < 4; ++i)
#pragma unroll
        for (int j = 0; j < 4; ++j)
          acc[i][j] = __builtin_amdgcn_mfma_f32_16x16x32_bf16(b[j], a[i], acc[i][j], 0, 0, 0);
    }
  }

  if (sel != 2) {
    unsigned short* Out = (sel == 0) ? Qb : Kb;
    const float scale = (sel == 0) ? QSCALE : 1.0f;
#pragma unroll
    for (int i = 0; i < 4; ++i)
#pragma unroll
      for (int j = 0; j < 4; ++j)
#pragma unroll
        for (int r = 0; r < 4; ++r) {
          int row = m0 + i * 16 + quad * 4 + r;
          int nl = n0 + j * 16 + c;
          int bi = row >> 11, li = row & 2047;
          int h = nl >> 6, d = nl & 63;
          Out[(((size_t)bi * NH + h) * LL + li) * HD + d] = f2bf(acc[i][j][r] * scale);
        }
  } else {
#pragma unroll
    for (int i = 0; i < 4; ++i) {
#pragma unroll
      for (int j = 0; j < 4; ++j)
#pragma unroll
        for (int r = 0; r < 4; ++r) {
          int n = n0 + j * 16 + quad * 4 + r;
          int s128 = (m0 & 64) + i * 16 + c;
          int m = (m0 & ~127) + vpos(s128);
          int h = n >> 6, d = n & 63;
          int bi = m0 >> 11;
          VT[(((size_t)bi * NH + h) * HD + d) * LL + (m & 2047)] = f2bf(acc[i][j][r]);
        }
    }
  }
}

__global__ __launch_bounds__(64) void o_proj_f(
    const unsigned short* __restrict__ A, const float* __restrict__ Wo,
    float* __restrict__ Out) {
  const int m0 = blockIdx.x * 64, n0 = blockIdx.y * 64;
  const int lane = threadIdx.x;
  const int c = lane & 15, quad = lane >> 4;

  f32x4 zero = {0.f, 0.f, 0.f, 0.f};
  f32x4 acc[4][4];
#pragma unroll
  for (int i = 0; i < 4; ++i)
#pragma unroll
    for (int j = 0; j < 4; ++j) acc[i][j] = zero;

  const unsigned short* ab = A + (size_t)(m0 + c) * DIMN + quad * 8;
  const float* bb = Wo + (size_t)(n0 + c) * DIMN + quad * 8;

  for (int k0 = 0; k0 < DIMN; k0 += 32) {
    s16x8 a[4], b[4];
#pragma unroll
    for (int i = 0; i < 4; ++i) a[i] = *(const s16x8*)(ab + i * 16 * DIMN + k0);
#pragma unroll
    for (int j = 0; j < 4; ++j) {
      const float* pp = bb + j * 16 * DIMN + k0;
      b[j] = cvt8(*(const float4*)pp, *(const float4*)(pp + 4));
    }
#pragma unroll
    for (int i = 0; i < 4; ++i)
#pragma unroll
      for (int j = 0; j < 4; ++j)
        acc[i][j] = __builtin_amdgcn_mfma_f32_16x16x32_bf16(a[i], b[j], acc[i][j], 0, 0, 0);
  }

#pragma unroll
  for (int i = 0; i < 4; ++i)
#pragma unroll
    for (int j = 0; j < 4; ++j)
#pragma unroll
      for (int r = 0; r < 4; ++r)
        Out[(size_t)(m0 + i * 16 + quad * 4 + r) * DIMN + n0 + j * 16 + c] = acc[i][j][r];
}

extern "C" void kernel_launch(void* const* d_in, const int* in_sizes, int n_in,
                              void* d_out, int out_size, void* d_ws, size_t ws_size,
                              hipStream_t stream) {
  const float* X = (const float*)d_in[0];
  const float* Wq = (const float*)d_in[1];
  const float* Wk = (const float*)d_in[2];
  const float* Wv = (const float*)d_in[3];
  const float* Wo = (const float*)d_in[4];
  float* Out = (float*)d_out;

  const size_t M1 = (size_t)1 << 20;
  unsigned short* ws16 = (unsigned short*)d_ws;

  if (ws_size >= (size_t)48 * 1024 * 1024) {
    unsigned short* Xb = ws16;            // 4M elems
    unsigned short* Wb = ws16 + 4 * M1;   // 4 x 1M (Wq,Wk,Wv,Wo contiguous)
    unsigned short* Qb = ws16 + 8 * M1;
    unsigned short* Kb = ws16 + 12 * M1;
    unsigned short* VT = ws16 + 16 * M1;
    unsigned short* AO = ws16 + 20 * M1;
    cvt_all<<<4096, 256, 0, stream>>>(X, Wq, Wk, Wv, Wo, ws16);
    gemm_qkv<<<768, 256, 0, stream>>>(Xb, Wb, Qb, Kb, VT);
    attn10<<<256, 512, 0, stream>>>(Qb, Kb, VT, AO);
    gemm_o<<<512, 256, 0, stream>>>(AO, Wb + 3 * M1, Out);
  } else {
    unsigned short* Qb = ws16;
    unsigned short* Kb = ws16 + 4 * M1;
    unsigned short* VT = ws16 + 8 * M1;
    unsigned short* AO = ws16 + 12 * M1;
    qkv_proj_f<<<dim3(64, 48), 64, 0, stream>>>(X, Wq, Wk, Wv, Qb, Kb, VT);
    attn10<<<256, 512, 0, stream>>>(Qb, Kb, VT, AO);
    o_proj_f<<<dim3(64, 16), 64, 0, stream>>>(AO, Wo, Out);
  }
}